// Round 2
// baseline (71.353 us; speedup 1.0000x reference)
//
#include <hip/hip_runtime.h>

// ConvCNP: out[b,m,o] = bias[o] + sum_c W[o,c] * y_out[b,m,c]
//   density = sum_n exp(-0.5 (x[b,n]-t[b,m])^2 / s_0^2)
//   conv_c  = sum_n y[b,n,c] * exp(-0.5 d / s_{c+1}^2)
//   y_out = [density, conv / (density + 1e-8)]
// Shapes: B=8, N=M=1024, C_IN=8, C_REP=9, C_OUT=16. All fp32.
//
// Kernel 1: blocks = B x (M/16) x NSPLIT. Each block: 16 m-values, 512 n-values.
//   256 thr = 8 m-lanes x 32 n-groups; each thread register-blocks R=2 m-values
//   (18 FMAs + 2 exps per 36B LDS read) -> LDS bytes/pair halved vs R=1.
//   Partial sums [NSPLIT][B][M][9] -> d_ws.
// Kernel 2: density division + W projection, one thread per (b,m,o).

#define B_     8
#define N_     1024
#define M_     1024
#define CIN    8
#define COUT   16
#define CREP   9
#define NSPLIT 2
#define NCHUNK (N_ / NSPLIT)    // 512 n per block
#define LM     8                // m-lanes
#define GN     32               // n-groups (LM*GN = 256 threads)
#define RM     2                // m-values per thread
#define MTILE  (LM * RM)        // 16 m per block
#define KITER  (NCHUNK / GN)    // 16

#if __has_builtin(__builtin_amdgcn_exp2f)
#define EXP2F(v) __builtin_amdgcn_exp2f(v)
#else
#define EXP2F(v) exp2f(v)
#endif

__global__ __launch_bounds__(256) void convcnp_partial(
    const float* __restrict__ x,      // [B,N]
    const float* __restrict__ y,      // [B,N,CIN]
    const float* __restrict__ t,      // [B,M]
    const float* __restrict__ sigma,  // [CREP]
    float* __restrict__ P)            // [NSPLIT,B,M,CREP] partials
{
    __shared__ float x_lds[NCHUNK];
    __shared__ float y_lds[NCHUNK * CIN];
    __shared__ float red[4][LM][RM][CREP];

    const int tid  = threadIdx.x;
    const int tile = blockIdx.x & 63;          // m-tile, fastest-varying
    const int s    = (blockIdx.x >> 6) & (NSPLIT - 1);
    const int bb   = blockIdx.x >> 7;
    const int m0   = tile * MTILE;
    const int n0   = s * NCHUNK;

    // ---- stage x chunk (2KB) + y chunk (16KB), float4 coalesced ----
    const float4* x4  = (const float4*)(x + bb * N_ + n0);
    float4*       xl4 = (float4*)x_lds;
    if (tid < NCHUNK / 4) xl4[tid] = x4[tid];
    const float4* y4  = (const float4*)(y + (bb * N_ + n0) * CIN);
    float4*       yl4 = (float4*)y_lds;
#pragma unroll
    for (int j = 0; j < NCHUNK * CIN / 4 / 256; ++j)
        yl4[tid + j * 256] = y4[tid + j * 256];

    // ---- exponent constants: kc = -0.5/s_c^2 * log2(e), s_c = exp(sigma_c) ----
    float kc[CREP];
#pragma unroll
    for (int c = 0; c < CREP; ++c)
        kc[c] = -0.72134752044f * EXP2F(-2.88539008178f * sigma[c]);
    bool uni = true;
#pragma unroll
    for (int c = 1; c < CREP; ++c) uni = uni && (kc[c] == kc[0]);

    const int   ml = tid & (LM - 1);           // m-lane 0..7
    const int   g  = tid >> 3;                 // n-group 0..31
    const float t0 = t[bb * M_ + m0 + ml];
    const float t1 = t[bb * M_ + m0 + ml + LM];

    float acc[RM][CREP];
#pragma unroll
    for (int r = 0; r < RM; ++r)
#pragma unroll
        for (int c = 0; c < CREP; ++c) acc[r][c] = 0.f;

    __syncthreads();

    if (uni) {
        const float k0 = kc[0];
#pragma unroll 4
        for (int k = 0; k < KITER; ++k) {
            const int    n  = g + (k << 5);
            const float  xv = x_lds[n];
            const float4 ya = *(const float4*)(y_lds + n * CIN);
            const float4 yb = *(const float4*)(y_lds + n * CIN + 4);
            float d0 = xv - t0; d0 *= d0;
            float d1 = xv - t1; d1 *= d1;
            const float w0 = EXP2F(k0 * d0);
            const float w1 = EXP2F(k0 * d1);
            acc[0][0] += w0;
            acc[0][1] += ya.x * w0; acc[0][2] += ya.y * w0;
            acc[0][3] += ya.z * w0; acc[0][4] += ya.w * w0;
            acc[0][5] += yb.x * w0; acc[0][6] += yb.y * w0;
            acc[0][7] += yb.z * w0; acc[0][8] += yb.w * w0;
            acc[1][0] += w1;
            acc[1][1] += ya.x * w1; acc[1][2] += ya.y * w1;
            acc[1][3] += ya.z * w1; acc[1][4] += ya.w * w1;
            acc[1][5] += yb.x * w1; acc[1][6] += yb.y * w1;
            acc[1][7] += yb.z * w1; acc[1][8] += yb.w * w1;
        }
    } else {
        // general per-channel scales
#pragma unroll 2
        for (int k = 0; k < KITER; ++k) {
            const int    n  = g + (k << 5);
            const float  xv = x_lds[n];
            const float4 ya = *(const float4*)(y_lds + n * CIN);
            const float4 yb = *(const float4*)(y_lds + n * CIN + 4);
            float d0 = xv - t0; d0 *= d0;
            float d1 = xv - t1; d1 *= d1;
            const float yr[CREP] = {1.f, ya.x, ya.y, ya.z, ya.w,
                                         yb.x, yb.y, yb.z, yb.w};
#pragma unroll
            for (int c = 0; c < CREP; ++c) {
                acc[0][c] += yr[c] * EXP2F(kc[c] * d0);
                acc[1][c] += yr[c] * EXP2F(kc[c] * d1);
            }
        }
    }

    // ---- reduce 8 n-groups within each wave (xor 8,16,32) ----
    const int wave = tid >> 6;
    const int lane = tid & 63;
#pragma unroll
    for (int r = 0; r < RM; ++r)
#pragma unroll
        for (int c = 0; c < CREP; ++c) {
            float v = acc[r][c];
            v += __shfl_xor(v, 8, 64);
            v += __shfl_xor(v, 16, 64);
            v += __shfl_xor(v, 32, 64);
            if (lane < LM) red[wave][lane][r][c] = v;
        }
    __syncthreads();

    // ---- reduce 4 waves, write partials ----
    if (tid < MTILE * CREP) {
        const int mm = tid / CREP;             // m-local 0..15
        const int c  = tid - mm * CREP;
        const int r  = mm >> 3, l = mm & 7;
        const float v = red[0][l][r][c] + red[1][l][r][c] +
                        red[2][l][r][c] + red[3][l][r][c];
        P[((s * B_ + bb) * M_ + m0 + mm) * CREP + c] = v;
    }
}

__global__ __launch_bounds__(256) void convcnp_proj(
    const float* __restrict__ P,      // [NSPLIT,B,M,CREP]
    const float* __restrict__ W,      // [COUT,CREP]
    const float* __restrict__ bias,   // [COUT]
    float* __restrict__ out)          // [B,M,COUT]
{
    const int gid = blockIdx.x * 256 + threadIdx.x;
    const int o   = gid & (COUT - 1);
    const int bm  = gid >> 4;
    const float* p0 = P + bm * CREP;
    const float* p1 = P + (size_t)B_ * M_ * CREP + bm * CREP;
    float p[CREP];
#pragma unroll
    for (int c = 0; c < CREP; ++c) p[c] = p0[c] + p1[c];
    const float dens = p[0];
    const float inv  = 1.0f / (dens + 1e-8f);
    float r = bias[o] + W[o * CREP] * dens;
#pragma unroll
    for (int c = 1; c < CREP; ++c) r += W[o * CREP + c] * (p[c] * inv);
    out[gid] = r;
}

extern "C" void kernel_launch(void* const* d_in, const int* in_sizes, int n_in,
                              void* d_out, int out_size, void* d_ws, size_t ws_size,
                              hipStream_t stream) {
    const float* x     = (const float*)d_in[0];
    const float* y     = (const float*)d_in[1];
    const float* t     = (const float*)d_in[2];
    const float* sigma = (const float*)d_in[3];
    const float* W     = (const float*)d_in[4];
    const float* bias  = (const float*)d_in[5];
    float*       out   = (float*)d_out;
    float*       P     = (float*)d_ws;   // NSPLIT*B*M*CREP*4 = 589824 B

    convcnp_partial<<<dim3(B_ * (M_ / MTILE) * NSPLIT), dim3(256), 0, stream>>>(
        x, y, t, sigma, P);
    convcnp_proj<<<dim3(B_ * M_ * COUT / 256), dim3(256), 0, stream>>>(
        P, W, bias, out);
}

// Round 3
// 69.559 us; speedup vs baseline: 1.0258x; 1.0258x over previous
//
#include <hip/hip_runtime.h>

// ConvCNP: out[b,m,o] = bias[o] + sum_c W[o,c] * y_out[b,m,c]
//   density = sum_n exp(-0.5 (x[b,n]-t[b,m])^2 / s_0^2)
//   conv_c  = sum_n y[b,n,c] * exp(-0.5 d / s_{c+1}^2)
//   y_out = [density, conv / (density + 1e-8)]
// Shapes: B=8, N=M=1024, C_IN=8, C_REP=9, C_OUT=16. All fp32.
//
// Single fused kernel (1 graph node, zero d_ws): dur_us is dominated by the
// harness's 268MB ws re-poison fill (~39.4us @ 6.8TB/s, measured R1/R2), so
// minimize our own node count + ws traffic. Block = 16 m-values x full N.
// 256 thr = 8 m-lanes x 32 n-groups, each thread register-blocks RM=2 m-values
// (18 FMAs + 2 exps per 36B of LDS reads -> VALU-bound, not LDS-bound).

#define B_    8
#define N_    1024
#define M_    1024
#define CIN   8
#define COUT  16
#define CREP  9
#define LM    8                 // m-lanes
#define GN    32                // n-groups (LM*GN = 256 threads)
#define RM    2                 // m-values per thread
#define MTILE (LM * RM)         // 16 m per block
#define KITER (N_ / GN)         // 32

#if __has_builtin(__builtin_amdgcn_exp2f)
#define EXP2F(v) __builtin_amdgcn_exp2f(v)
#else
#define EXP2F(v) exp2f(v)
#endif

__global__ __launch_bounds__(256) void convcnp_fused(
    const float* __restrict__ x,      // [B,N]
    const float* __restrict__ y,      // [B,N,CIN]
    const float* __restrict__ t,      // [B,M]
    const float* __restrict__ sigma,  // [CREP]
    const float* __restrict__ W,      // [COUT,CREP]
    const float* __restrict__ bias,   // [COUT]
    float* __restrict__ out)          // [B,M,COUT]
{
    __shared__ float x_lds[N_];                 // 4 KB
    __shared__ float y_lds[N_ * CIN];           // 32 KB
    __shared__ float red[4][LM][RM][CREP];      // 2.3 KB
    __shared__ float fin[MTILE][CREP];

    const int tid  = threadIdx.x;
    const int bb   = blockIdx.x >> 6;           // 64 m-tiles per batch
    const int tile = blockIdx.x & 63;
    const int m0   = tile * MTILE;

    // ---- stage x (4KB) + y (32KB) into LDS, float4 coalesced ----
    const float4* x4  = (const float4*)(x + bb * N_);
    float4*       xl4 = (float4*)x_lds;
    xl4[tid] = x4[tid];
    const float4* y4  = (const float4*)(y + bb * N_ * CIN);
    float4*       yl4 = (float4*)y_lds;
#pragma unroll
    for (int j = 0; j < 8; ++j) yl4[tid + j * 256] = y4[tid + j * 256];

    // ---- exponent constants: kc = -0.5/s_c^2 * log2(e), s_c = exp(sigma_c) ----
    float kc[CREP];
#pragma unroll
    for (int c = 0; c < CREP; ++c)
        kc[c] = -0.72134752044f * EXP2F(-2.88539008178f * sigma[c]);
    bool uni = true;
#pragma unroll
    for (int c = 1; c < CREP; ++c) uni = uni && (kc[c] == kc[0]);

    const int   ml = tid & (LM - 1);            // m-lane 0..7
    const int   g  = tid >> 3;                  // n-group 0..31
    const float t0 = t[bb * M_ + m0 + ml];
    const float t1 = t[bb * M_ + m0 + ml + LM];

    float acc[RM][CREP];
#pragma unroll
    for (int r = 0; r < RM; ++r)
#pragma unroll
        for (int c = 0; c < CREP; ++c) acc[r][c] = 0.f;

    __syncthreads();

    if (uni) {
        const float k0 = kc[0];
#pragma unroll 4
        for (int k = 0; k < KITER; ++k) {
            const int    n  = g + (k << 5);
            const float  xv = x_lds[n];
            const float4 ya = *(const float4*)(y_lds + n * CIN);
            const float4 yb = *(const float4*)(y_lds + n * CIN + 4);
            float d0 = xv - t0; d0 *= d0;
            float d1 = xv - t1; d1 *= d1;
            const float w0 = EXP2F(k0 * d0);
            const float w1 = EXP2F(k0 * d1);
            acc[0][0] += w0;
            acc[0][1] += ya.x * w0; acc[0][2] += ya.y * w0;
            acc[0][3] += ya.z * w0; acc[0][4] += ya.w * w0;
            acc[0][5] += yb.x * w0; acc[0][6] += yb.y * w0;
            acc[0][7] += yb.z * w0; acc[0][8] += yb.w * w0;
            acc[1][0] += w1;
            acc[1][1] += ya.x * w1; acc[1][2] += ya.y * w1;
            acc[1][3] += ya.z * w1; acc[1][4] += ya.w * w1;
            acc[1][5] += yb.x * w1; acc[1][6] += yb.y * w1;
            acc[1][7] += yb.z * w1; acc[1][8] += yb.w * w1;
        }
    } else {
        // general per-channel scales
#pragma unroll 2
        for (int k = 0; k < KITER; ++k) {
            const int    n  = g + (k << 5);
            const float  xv = x_lds[n];
            const float4 ya = *(const float4*)(y_lds + n * CIN);
            const float4 yb = *(const float4*)(y_lds + n * CIN + 4);
            float d0 = xv - t0; d0 *= d0;
            float d1 = xv - t1; d1 *= d1;
            const float yr[CREP] = {1.f, ya.x, ya.y, ya.z, ya.w,
                                         yb.x, yb.y, yb.z, yb.w};
#pragma unroll
            for (int c = 0; c < CREP; ++c) {
                acc[0][c] += yr[c] * EXP2F(kc[c] * d0);
                acc[1][c] += yr[c] * EXP2F(kc[c] * d1);
            }
        }
    }

    // ---- reduce 8 n-groups within each wave (xor 8,16,32) ----
    const int wave = tid >> 6;
    const int lane = tid & 63;
#pragma unroll
    for (int r = 0; r < RM; ++r)
#pragma unroll
        for (int c = 0; c < CREP; ++c) {
            float v = acc[r][c];
            v += __shfl_xor(v, 8, 64);
            v += __shfl_xor(v, 16, 64);
            v += __shfl_xor(v, 32, 64);
            if (lane < LM) red[wave][lane][r][c] = v;
        }
    __syncthreads();

    // ---- reduce 4 waves ----
    if (tid < MTILE * CREP) {
        const int mm = tid / CREP;              // m-local 0..15
        const int c  = tid - mm * CREP;
        const int r  = mm >> 3, l = mm & 7;
        fin[mm][c] = red[0][l][r][c] + red[1][l][r][c] +
                     red[2][l][r][c] + red[3][l][r][c];
    }
    __syncthreads();

    // ---- epilogue: one (m, o) output per thread ----
    const int o = tid & 15;
    const int m = tid >> 4;
    const float dens = fin[m][0];
    const float inv  = 1.0f / (dens + 1e-8f);
    float r = bias[o] + W[o * CREP] * dens;
#pragma unroll
    for (int c = 1; c < CREP; ++c) r += W[o * CREP + c] * (fin[m][c] * inv);
    out[(bb * M_ + m0 + m) * COUT + o] = r;
}

extern "C" void kernel_launch(void* const* d_in, const int* in_sizes, int n_in,
                              void* d_out, int out_size, void* d_ws, size_t ws_size,
                              hipStream_t stream) {
    const float* x     = (const float*)d_in[0];
    const float* y     = (const float*)d_in[1];
    const float* t     = (const float*)d_in[2];
    const float* sigma = (const float*)d_in[3];
    const float* W     = (const float*)d_in[4];
    const float* bias  = (const float*)d_in[5];
    float*       out   = (float*)d_out;

    convcnp_fused<<<dim3(B_ * (M_ / MTILE)), dim3(256), 0, stream>>>(
        x, y, t, sigma, W, bias, out);
}